// Round 11
// baseline (37.790 us; speedup 1.0000x reference)
//
#include <hip/hip_runtime.h>

typedef unsigned long long u64;

#define NPTS 8192
#define DIM  512
#define NK   64
#define TM   256            // rows per tile
#define KP   8              // K-split parts
#define KD   64             // dims per part
#define NT   (NPTS/TM)      // 32 tiles
#define APQ  17             // LDS pitch in float4 (68 floats)

// workspace layout (float offsets)
#define WS_DOT  0                       // [KP][NK][NPTS] = 16 MB
#define WS_STAT (KP * NK * NPTS)        // [KP][NPTS] float2 = 512 KB

// ---------------------------------------------------------------------------
// GEMM: 256 blocks (32 tiles x 8 K-parts) x 256 threads, 1 block/CU (87 KB
// LDS). 8x8 microtile: per 4-dim macro-step a thread does 8 A-reads + 8
// B-reads (b128) per 256 FMAs -> LDS-instr:FMA-instr = 16:256, ~1.5x VALU
// (R8/R9's 4x4 was 2:16 = 3x LDS-bound; instr count, not bytes, is the pipe
// cost). A-rows per microtile strided 32 so each read instr touches 32
// consecutive rows (pitch 17 f4 spreads bank groups at the b128 floor);
// B-reads are 2-address broadcasts. One barrier total; stats ride on av
// registers; no prep kernel (B gathered via cid from L2 per block; out[0]
// zeroed here, stream-ordered before epi's atomics).
// ---------------------------------------------------------------------------
__global__ __launch_bounds__(256) void gemm_kernel(
    const float* __restrict__ f, const int* __restrict__ cid,
    float* __restrict__ ws, float* __restrict__ out)
{
    __shared__ float4 Al[TM * APQ];   // 69.6 KB
    __shared__ float4 Bl[NK * APQ];   // 17.4 KB

    const int t     = threadIdx.x;
    const int tile  = blockIdx.x >> 3;
    const int kp    = blockIdx.x & 7;
    const int kbase = kp * KD;
    if (blockIdx.x == 0 && t == 0) out[0] = 0.f;

    // ---- stage A: thread (s=t&15 f4-slot, rb=t>>4); wave instr = 4 rows x
    // 256B contiguous global segments. 16 instrs cover 256 rows x 64 dims.
    {
        const int s = t & 15, rb = t >> 4;
        const float* base = f + (size_t)(tile * TM) * DIM + kbase + s * 4;
        #pragma unroll
        for (int m = 0; m < 16; ++m) {
            const int row = rb + 16 * m;
            Al[row * APQ + s] = *(const float4*)(base + (size_t)row * DIM);
        }
    }
    // ---- stage B: gather 64 centroid rows' 64-dim slice via cid (L2-hot;
    // every block reads the same 128 KB of centroid rows).
    {
        const int col = t & 63, q = t >> 6;
        const float* src = f + (size_t)cid[col] * DIM + kbase + q * 16;
        #pragma unroll
        for (int j = 0; j < 4; ++j)
            Bl[col * APQ + q * 4 + j] = *(const float4*)(src + 4 * j);
    }
    __syncthreads();          // the only barrier

    const int rowg = t & 31;          // microtile rows: rowg + 32*i
    const int colg = t >> 5;          // 0..7 -> cols colg*8 .. +8
    float acc[8][8];
    #pragma unroll
    for (int i = 0; i < 8; ++i)
        #pragma unroll
        for (int c = 0; c < 8; ++c) acc[i][c] = 0.f;
    float sp[8], qp[8];
    #pragma unroll
    for (int i = 0; i < 8; ++i) { sp[i] = 0.f; qp[i] = 0.f; }

    #pragma unroll 2
    for (int g = 0; g < 16; ++g) {    // 16 macro-steps of 4 dims
        float4 av[8];
        #pragma unroll
        for (int i = 0; i < 8; ++i)
            av[i] = Al[(rowg + 32 * i) * APQ + g];
        if (colg == 0) {              // one stats owner per row (wave 0 only)
            #pragma unroll
            for (int i = 0; i < 8; ++i) {
                sp[i] += (av[i].x + av[i].y) + (av[i].z + av[i].w);
                qp[i] = fmaf(av[i].x, av[i].x, qp[i]);
                qp[i] = fmaf(av[i].y, av[i].y, qp[i]);
                qp[i] = fmaf(av[i].z, av[i].z, qp[i]);
                qp[i] = fmaf(av[i].w, av[i].w, qp[i]);
            }
        }
        #pragma unroll
        for (int c = 0; c < 8; ++c) {
            const float4 bv = Bl[(colg * 8 + c) * APQ + g];  // 2-addr bcast
            #pragma unroll
            for (int i = 0; i < 8; ++i) {
                acc[i][c] = fmaf(av[i].x, bv.x, acc[i][c]);
                acc[i][c] = fmaf(av[i].y, bv.y, acc[i][c]);
                acc[i][c] = fmaf(av[i].z, bv.z, acc[i][c]);
                acc[i][c] = fmaf(av[i].w, bv.w, acc[i][c]);
            }
        }
    }

    // ---- store partials [kp][col][pt]: 32 consecutive pts/lane-group ----
    const int pbase = tile * TM + rowg;
    #pragma unroll
    for (int c = 0; c < 8; ++c) {
        float* dst = ws + WS_DOT
                   + (size_t)(kp * NK + colg * 8 + c) * NPTS + pbase;
        #pragma unroll
        for (int i = 0; i < 8; ++i) dst[32 * i] = acc[i][c];
    }
    if (colg == 0) {
        #pragma unroll
        for (int i = 0; i < 8; ++i)
            ((float2*)(ws + WS_STAT))[(size_t)kp * NPTS + pbase + 32 * i] =
                make_float2(sp[i], qp[i]);
    }
}

// ---------------------------------------------------------------------------
// Epilogue: 512 blocks x 256 threads (2048 waves). Block owns 16 points;
// thread (p=t&15, cg=t>>4) sums 4 cols x 8 kp partials (coalesced), packed-
// key min (first-index tie-break); centroid stats gathered from point stats
// via cid (no prep kernel); LDS combine; last-write-wins override; energy.
// ---------------------------------------------------------------------------
__global__ __launch_bounds__(256) void epi_kernel(
    const float* __restrict__ ws, const int* __restrict__ cid,
    float* __restrict__ out)
{
    __shared__ u64   keys[16][16];
    __shared__ float cqL[NK], csL[NK];
    __shared__ int   cidL[NK];

    const int t  = threadIdx.x;
    const int p  = t & 15;
    const int cg = t >> 4;             // 0..15, 4 cols each
    const int gi = blockIdx.x * 16 + p;
    const float2* st = (const float2*)(ws + WS_STAT);

    if (t < NK) {                      // centroid stats = stats of point cid[t]
        const int cr = cid[t];
        float s = 0.f, q = 0.f;
        #pragma unroll
        for (int kp = 0; kp < KP; ++kp) {
            float2 v = st[(size_t)kp * NPTS + cr]; s += v.x; q += v.y;
        }
        cqL[t] = q; csL[t] = s; cidL[t] = cr;
    }
    float s = 0.f, q = 0.f;            // this point's stats
    #pragma unroll
    for (int kp = 0; kp < KP; ++kp) {
        float2 v = st[(size_t)kp * NPTS + gi]; s += v.x; q += v.y;
    }
    __syncthreads();

    u64 key = ~0ull;
    #pragma unroll
    for (int c = 0; c < 4; ++c) {
        const int col = cg * 4 + c;
        float dot = 0.f;
        #pragma unroll
        for (int kp = 0; kp < KP; ++kp)
            dot += ws[WS_DOT + (size_t)(kp * NK + col) * NPTS + gi];
        float d2 = q + cqL[col] - 2.f * dot + 2.0e-6f * (s - csL[col])
                 + 5.12e-10f;
        float dist = sqrtf(fmaxf(d2, 0.f));
        u64 kk = (((u64)__float_as_uint(dist)) << 6) | (unsigned)col;
        key = (kk < key) ? kk : key;
    }
    keys[cg][p] = key;
    __syncthreads();

    if (t < 16) {
        u64 kmin = keys[0][t];
        #pragma unroll
        for (int j = 1; j < 16; ++j) {
            u64 o = keys[j][t];
            kmin = (o < kmin) ? o : kmin;
        }
        const int gp = blockIdx.x * 16 + t;
        float y = (float)(unsigned)(kmin & 63ull);
        for (int k = 0; k < NK; ++k)
            if (cidL[k] == gp) y = (float)k;          // last write wins
        out[1 + gp] = y;
        float e = __uint_as_float((unsigned)(kmin >> 6));
        e += __shfl_xor(e, 1); e += __shfl_xor(e, 2);
        e += __shfl_xor(e, 4); e += __shfl_xor(e, 8);
        if (t == 0) atomicAdd(out, -e);
    }
}

extern "C" void kernel_launch(void* const* d_in, const int* in_sizes, int n_in,
                              void* d_out, int out_size, void* d_ws, size_t ws_size,
                              hipStream_t stream) {
    const float* f   = (const float*)d_in[0];
    const int*   cid = (const int*)d_in[1];
    float*       out = (float*)d_out;
    float*       ws  = (float*)d_ws;     // ~16.5 MB used

    gemm_kernel<<<NT * KP, 256, 0, stream>>>(f, cid, ws, out);
    epi_kernel<<<NPTS / 16, 256, 0, stream>>>(ws, cid, out);
}

// Round 12
// 35.049 us; speedup vs baseline: 1.0782x; 1.0782x over previous
//
#include <hip/hip_runtime.h>

typedef unsigned long long u64;

#define NPTS 8192
#define DIM  512
#define NK   64
#define TM   64             // rows per tile
#define KP   8              // K-split parts
#define KD   64             // dims per part
#define NT   (NPTS/TM)      // 128 tiles
#define PIT  17             // LDS pitch in float4 (68 floats, == 4 mod 8 words)

// workspace layout (float offsets)
#define WS_DOT  0                       // [KP][NK][NPTS] = 16.8 MB
#define WS_STAT (KP * NK * NPTS)        // [KP][NPTS] float2

// ---------------------------------------------------------------------------
// GEMM: 1024 blocks (128 tiles x 8 K-parts) x 128 threads = 2048 waves;
// 34.8 KB LDS -> exactly 4 blocks/CU = 8 waves/CU. Micro-tile 8x4,
// r = 12 b128 : 128 FMA = 1:10.7. Bank-conflict-free BY CONSTRUCTION:
//  - A reads: rows rg+8i, lanes rg=0..7 -> 8 CONSECUTIVE rows/instr, banks
//    4(row+g) mod 32 cover all groups; 8-way same-addr broadcast across cgs.
//    (R10 bug: rows/cols a multiple-of-8 apart at 16B-aligned pitch ALWAYS
//    collide; consecutive-in-instr is the only conflict-free b128 pattern.)
//  - B reads: cols cg+16c -> 16 consecutive cols/instr -> 2-way = free.
// One barrier; B gathered via cid from L2 (all blocks share 128 KB); stats
// computed from LDS by threads<64; out[0] zeroed here (stream-ordered).
// ---------------------------------------------------------------------------
__global__ __launch_bounds__(128) void gemm_kernel(
    const float* __restrict__ f, const int* __restrict__ cid,
    float* __restrict__ ws, float* __restrict__ out)
{
    __shared__ float4 Al[TM * PIT];   // 17.4 KB  [row][f4slot]
    __shared__ float4 Bl[NK * PIT];   // 17.4 KB  [col][f4slot]

    const int t     = threadIdx.x;
    const int tile  = blockIdx.x >> 3;
    const int kp    = blockIdx.x & 7;
    const int kbase = kp * KD;
    if (blockIdx.x == 0 && t == 0) out[0] = 0.f;

    // ---- stage A: (sg=t&15 f4-slot, rb=t>>4): instr = 4 rows x 256B ----
    {
        const int sg = t & 15, rb = t >> 4;
        const float* base = f + (size_t)(tile * TM + rb) * DIM + kbase + sg * 4;
        #pragma unroll
        for (int m = 0; m < 8; ++m)
            Al[(rb + 8 * m) * PIT + sg] =
                *(const float4*)(base + (size_t)(8 * m) * DIM);
    }
    // ---- stage B: (col=t&63, q=t>>6): cid-gather, 8 f4 each, L2-hot ----
    {
        const int col = t & 63, q = t >> 6;
        const float* src = f + (size_t)cid[col] * DIM + kbase + q * 32;
        #pragma unroll
        for (int j = 0; j < 8; ++j)
            Bl[col * PIT + q * 8 + j] = *(const float4*)(src + 4 * j);
    }
    __syncthreads();          // the only barrier

    // ---- per-point stats for this K-slice (threads<64, free bank pattern)
    if (t < TM) {
        float s = 0.f, q = 0.f;
        #pragma unroll
        for (int sl = 0; sl < 16; ++sl) {
            float4 v = Al[t * PIT + sl];
            s += (v.x + v.y) + (v.z + v.w);
            q = fmaf(v.x, v.x, q); q = fmaf(v.y, v.y, q);
            q = fmaf(v.z, v.z, q); q = fmaf(v.w, v.w, q);
        }
        ((float2*)(ws + WS_STAT))[(size_t)kp * NPTS + tile * TM + t] =
            make_float2(s, q);
    }

    // ---- compute: rows rg+8i (i=0..7), cols cg+16c (c=0..3) ----
    const int rg = t & 7;
    const int cg = t >> 3;            // 0..15
    float acc[8][4];
    #pragma unroll
    for (int i = 0; i < 8; ++i)
        #pragma unroll
        for (int c = 0; c < 4; ++c) acc[i][c] = 0.f;

    #pragma unroll 4
    for (int g = 0; g < 16; ++g) {    // 16 macro-steps of 4 dims
        float4 av[8], bv[4];
        #pragma unroll
        for (int i = 0; i < 8; ++i) av[i] = Al[(rg + 8 * i) * PIT + g];
        #pragma unroll
        for (int c = 0; c < 4; ++c) bv[c] = Bl[(cg + 16 * c) * PIT + g];
        #pragma unroll
        for (int i = 0; i < 8; ++i)
            #pragma unroll
            for (int c = 0; c < 4; ++c) {
                acc[i][c] = fmaf(av[i].x, bv[c].x, acc[i][c]);
                acc[i][c] = fmaf(av[i].y, bv[c].y, acc[i][c]);
                acc[i][c] = fmaf(av[i].z, bv[c].z, acc[i][c]);
                acc[i][c] = fmaf(av[i].w, bv[c].w, acc[i][c]);
            }
    }

    // ---- store partials [kp][col][pt] (8 consecutive pts per col/instr) ----
    const int pbase = tile * TM + rg;
    #pragma unroll
    for (int c = 0; c < 4; ++c) {
        float* dst = ws + WS_DOT
                   + (size_t)(kp * NK + cg + 16 * c) * NPTS + pbase;
        #pragma unroll
        for (int i = 0; i < 8; ++i) dst[8 * i] = acc[i][c];
    }
}

// ---------------------------------------------------------------------------
// Epilogue: 512 blocks x 256 threads (2048 waves). Block owns 16 points;
// thread (p=t&15, cg=t>>4) sums 4 cols x 8 kp partials (coalesced), packed-
// key min (first-index tie-break); centroid stats gathered from point stats
// via cid; LDS combine; last-write-wins override; energy.
// ---------------------------------------------------------------------------
__global__ __launch_bounds__(256) void epi_kernel(
    const float* __restrict__ ws, const int* __restrict__ cid,
    float* __restrict__ out)
{
    __shared__ u64   keys[16][16];
    __shared__ float cqL[NK], csL[NK];
    __shared__ int   cidL[NK];

    const int t  = threadIdx.x;
    const int p  = t & 15;
    const int cg = t >> 4;             // 0..15, 4 cols each
    const int gi = blockIdx.x * 16 + p;
    const float2* st = (const float2*)(ws + WS_STAT);

    if (t < NK) {                      // centroid stats = stats of point cid[t]
        const int cr = cid[t];
        float s = 0.f, q = 0.f;
        #pragma unroll
        for (int kp = 0; kp < KP; ++kp) {
            float2 v = st[(size_t)kp * NPTS + cr]; s += v.x; q += v.y;
        }
        cqL[t] = q; csL[t] = s; cidL[t] = cr;
    }
    float s = 0.f, q = 0.f;            // this point's stats
    #pragma unroll
    for (int kp = 0; kp < KP; ++kp) {
        float2 v = st[(size_t)kp * NPTS + gi]; s += v.x; q += v.y;
    }
    __syncthreads();

    u64 key = ~0ull;
    #pragma unroll
    for (int c = 0; c < 4; ++c) {
        const int col = cg * 4 + c;
        float dot = 0.f;
        #pragma unroll
        for (int kp = 0; kp < KP; ++kp)
            dot += ws[WS_DOT + (size_t)(kp * NK + col) * NPTS + gi];
        float d2 = q + cqL[col] - 2.f * dot + 2.0e-6f * (s - csL[col])
                 + 5.12e-10f;
        float dist = sqrtf(fmaxf(d2, 0.f));
        u64 kk = (((u64)__float_as_uint(dist)) << 6) | (unsigned)col;
        key = (kk < key) ? kk : key;
    }
    keys[cg][p] = key;
    __syncthreads();

    if (t < 16) {
        u64 kmin = keys[0][t];
        #pragma unroll
        for (int j = 1; j < 16; ++j) {
            u64 o = keys[j][t];
            kmin = (o < kmin) ? o : kmin;
        }
        const int gp = blockIdx.x * 16 + t;
        float y = (float)(unsigned)(kmin & 63ull);
        for (int k = 0; k < NK; ++k)
            if (cidL[k] == gp) y = (float)k;          // last write wins
        out[1 + gp] = y;
        float e = __uint_as_float((unsigned)(kmin >> 6));
        e += __shfl_xor(e, 1); e += __shfl_xor(e, 2);
        e += __shfl_xor(e, 4); e += __shfl_xor(e, 8);
        if (t == 0) atomicAdd(out, -e);
    }
}

extern "C" void kernel_launch(void* const* d_in, const int* in_sizes, int n_in,
                              void* d_out, int out_size, void* d_ws, size_t ws_size,
                              hipStream_t stream) {
    const float* f   = (const float*)d_in[0];
    const int*   cid = (const int*)d_in[1];
    float*       out = (float*)d_out;
    float*       ws  = (float*)d_ws;     // ~17 MB used

    gemm_kernel<<<NT * KP, 128, 0, stream>>>(f, cid, ws, out);
    epi_kernel<<<NPTS / 16, 256, 0, stream>>>(ws, cid, out);
}